// Round 4
// baseline (874.657 us; speedup 1.0000x reference)
//
#include <hip/hip_runtime.h>
#include <math.h>

#define N_NODES 100000
#define N_EDGES 200000
#define NNZ_    1600000
#define INC  128
#define OUTC 128
#define STAR_ 64
#define NEG 0.2f
#define MAXE 32   // per-edge cached incidences (deg ~ Poisson(8))
#define MAXN 64   // per-node cached incidences (deg ~ Poisson(16))
#define NBUCK 300000   // 200000 edge buckets + 100000 node buckets
#define NCOPY 8

typedef __attribute__((ext_vector_type(8))) short bf16x8_t;
typedef __attribute__((ext_vector_type(4))) float f32x4_t;

__device__ __forceinline__ float leaky(float x){ return x > 0.f ? x : NEG*x; }
__device__ __forceinline__ float elu1(float x){ return x > 0.f ? x : __expf(x)-1.f; }
__device__ __forceinline__ unsigned short f2bf(float f){
  unsigned u = __float_as_uint(f);
  unsigned r = u + 0x7FFFu + ((u >> 16) & 1u);
  return (unsigned short)(r >> 16);
}
__device__ __forceinline__ float bf2f(unsigned short h){
  return __uint_as_float(((unsigned)h) << 16);
}

// ---- cvt: WcatT[256][128] = [Wx|Wv]^T bf16 ; WtT[128][192] = Wt^T bf16 ----
__global__ void k_cvt(const float* __restrict__ Wx, const float* __restrict__ Wv,
                      const float* __restrict__ Wt,
                      unsigned short* __restrict__ WcatT, unsigned short* __restrict__ WtT){
  const int i = blockIdx.x*256 + threadIdx.x;
  if (i < 256*128){
    const int n = i >> 7, k = i & 127;
    const float v = (n < 128) ? Wx[k*128 + n] : Wv[k*128 + (n-128)];
    WcatT[n*128 + k] = f2bf(v);
  }
  const int j = i - 256*128;
  if (j >= 0 && j < 128*192){
    const int n = j / 192, k = j - n*192;
    WtT[n*192 + k] = f2bf(Wt[k*128 + n]);
  }
}

// ---- GEMM1 (MFMA): [Xinit|Xfeat] = X @ [Wx|Wv] + [bx|bv]; Xinit fp32 -> d_out, Xfeat bf16 ----
__global__ __launch_bounds__(256) void k_gemm1(const float* __restrict__ X,
    const unsigned short* __restrict__ WcatT,
    const float* __restrict__ bx, const float* __restrict__ bv,
    float* __restrict__ Xinit, unsigned short* __restrict__ Xfb){
  __shared__ unsigned short xb[16][136];
  const int tid = threadIdx.x;
  const int lane = tid & 63, w = tid >> 6;
  const int quad = lane >> 4, l16 = lane & 15;
  const int r0 = blockIdx.x * 16;
  {
    const int r = tid >> 4;
    const int c0 = (tid & 15) * 8;
    const float4 a4 = *(const float4*)&X[(size_t)(r0+r)*INC + c0];
    const float4 b4 = *(const float4*)&X[(size_t)(r0+r)*INC + c0 + 4];
    bf16x8_t pk;
    pk[0]=(short)f2bf(a4.x); pk[1]=(short)f2bf(a4.y); pk[2]=(short)f2bf(a4.z); pk[3]=(short)f2bf(a4.w);
    pk[4]=(short)f2bf(b4.x); pk[5]=(short)f2bf(b4.y); pk[6]=(short)f2bf(b4.z); pk[7]=(short)f2bf(b4.w);
    *(bf16x8_t*)&xb[r][c0] = pk;
  }
  __syncthreads();
  f32x4_t acc[4] = {{0,0,0,0},{0,0,0,0},{0,0,0,0},{0,0,0,0}};
  const int n_base = w*64 + l16;
  for (int s = 0; s < 4; ++s){
    const bf16x8_t af = *(const bf16x8_t*)&xb[l16][s*32 + quad*8];
    #pragma unroll
    for (int nt = 0; nt < 4; ++nt){
      const int n = n_base + nt*16;
      const bf16x8_t bf = *(const bf16x8_t*)&WcatT[(size_t)n*128 + s*32 + quad*8];
      acc[nt] = __builtin_amdgcn_mfma_f32_16x16x32_bf16(af, bf, acc[nt], 0, 0, 0);
    }
  }
  #pragma unroll
  for (int nt = 0; nt < 4; ++nt){
    const int n = n_base + nt*16;
    const float bias = (n < 128) ? bx[n] : bv[n-128];
    #pragma unroll
    for (int r = 0; r < 4; ++r){
      const int m = quad*4 + r;
      const float val = acc[nt][r] + bias;
      if (n < 128) Xinit[(size_t)(r0+m)*OUTC + n] = val;
      else         Xfb[(size_t)(r0+m)*OUTC + (n-128)] = f2bf(val);
    }
  }
}

// ---- scores = Xfeat @ a ----
__global__ __launch_bounds__(256) void k_scores(const unsigned short* __restrict__ Xfb,
    const float* __restrict__ a, float* __restrict__ scores){
  const int lane = threadIdx.x & 63;
  const int w = threadIdx.x >> 6;
  const int r = blockIdx.x * 4 + w;
  const unsigned pair = *(const unsigned*)&Xfb[(size_t)r*OUTC + lane*2];
  float p = bf2f((unsigned short)(pair & 0xffff)) * a[lane*2]
          + bf2f((unsigned short)(pair >> 16))    * a[lane*2+1];
  #pragma unroll
  for (int o = 32; o; o >>= 1) p += __shfl_xor(p, o, 64);
  if (lane == 0) scores[r] = p;
}

// ---------------- CSR build (XCD-privatized counters) ----------------
// priv[c][b], b in [0,200000)=edge buckets, [200000,300000)=node buckets.
__global__ void k_hist(const int* __restrict__ V, const int* __restrict__ E,
                       int* __restrict__ priv) {
  const int i = blockIdx.x*256 + threadIdx.x;
  const int c = blockIdx.x & (NCOPY-1);
  int* base = priv + c*NBUCK;
  atomicAdd(&base[E[i]], 1);
  atomicAdd(&base[200000 + V[i]], 1);
}

// cnt[b] = sum over copies
__global__ void k_total(const int* __restrict__ priv, int* __restrict__ cnt) {
  const int b = blockIdx.x*256 + threadIdx.x;
  if (b >= NBUCK) return;
  int s = 0;
  #pragma unroll
  for (int c = 0; c < NCOPY; ++c) s += priv[c*NBUCK + b];
  cnt[b] = s;
}

__global__ void k_scan_block(const int* __restrict__ in, int* __restrict__ out,
                             int* __restrict__ partials, int n) {
  __shared__ int s[256];
  const int tid = threadIdx.x;
  const int i = blockIdx.x*256 + tid;
  const int v = (i < n) ? in[i] : 0;
  s[tid] = v; __syncthreads();
  for (int o = 1; o < 256; o <<= 1) {
    const int u = (tid >= o) ? s[tid-o] : 0;
    __syncthreads();
    s[tid] += u;
    __syncthreads();
  }
  if (i < n) out[i] = s[tid] - v;
  if (tid == 255) partials[blockIdx.x] = s[255];
}

__global__ void k_scan_partials(int* partials, int nb) {
  __shared__ int s[1024];
  const int tid = threadIdx.x;
  const int v = (tid < nb) ? partials[tid] : 0;
  s[tid] = v; __syncthreads();
  for (int o = 1; o < 1024; o <<= 1) {
    const int u = (tid >= o) ? s[tid-o] : 0;
    __syncthreads();
    s[tid] += u;
    __syncthreads();
  }
  if (tid < nb) partials[tid] = s[tid] - v;
}

__global__ void k_add_off(int* __restrict__ out, const int* __restrict__ partials, int n) {
  const int i = blockIdx.x*256 + threadIdx.x;
  if (i < n) out[i] += partials[blockIdx.x];
}

// priv[c][b] <- starts[b] + sum_{c'<c} priv[c'][b]   (running slot cursor per copy)
__global__ void k_bases(int* __restrict__ priv,
                        const int* __restrict__ startsE, const int* __restrict__ startsV) {
  const int b = blockIdx.x*256 + threadIdx.x;
  if (b >= NBUCK) return;
  int s = (b < 200000) ? startsE[b] : startsV[b - 200000];
  #pragma unroll
  for (int c = 0; c < NCOPY; ++c) {
    const int t = priv[c*NBUCK + b];
    priv[c*NBUCK + b] = s;
    s += t;
  }
}

// slot = atomicAdd(local-copy cursor); scatter store gathered value
__global__ void k_fill(const int* __restrict__ V, const int* __restrict__ E,
    int* __restrict__ priv, int* __restrict__ vIdxE, int* __restrict__ eIdxV) {
  const int i = blockIdx.x*256 + threadIdx.x;
  const int c = blockIdx.x & (NCOPY-1);
  int* base = priv + c*NBUCK;
  const int e = E[i], v = V[i];
  const int se = atomicAdd(&base[e], 1);
  const int sv = atomicAdd(&base[200000 + v], 1);
  vIdxE[se] = v;
  eIdxV[sv] = e;
}

// ---- edge kernel: softmax + v2e aggregate + elu + MFMA [msg,S]@Wt + bt -> Y bf16 ----
__global__ __launch_bounds__(256) void k_edge(
    const int* __restrict__ cntE, const int* __restrict__ startsE,
    const int* __restrict__ vIdxE,
    const float* __restrict__ scores, const unsigned short* __restrict__ Xfb,
    const float* __restrict__ S, const unsigned short* __restrict__ WtT,
    const float* __restrict__ bt, unsigned short* __restrict__ Ybf) {
  __shared__ int   wvs[16][MAXE];
  __shared__ float wws[16][MAXE];
  __shared__ unsigned short msg[16][200];
  __shared__ float ms[16], dens[16];
  __shared__ int   degs[16], sts[16];
  const int tid = threadIdx.x;
  const int lane = tid & 63, w = tid >> 6;
  const int e0 = blockIdx.x * 16;

  for (int p = tid; p < 16*MAXE; p += 256) { ((int*)wvs)[p] = 0; ((float*)wws)[p] = 0.f; }
  __syncthreads();

  // phase A: per-edge softmax scalars (wave w owns edges w*4 .. w*4+3)
  for (int q = 0; q < 4; ++q) {
    const int t = w*4 + q;
    const int e = e0 + t;
    const int deg = cntE[e], st = startsE[e];
    if (deg <= 64) {
      // fast path: one incidence per lane, single gather
      int v = 0; float ls = -INFINITY;
      if (lane < deg) { v = vIdxE[st + lane]; ls = leaky(scores[v]); }
      float m = ls;
      #pragma unroll
      for (int o = 32; o; o >>= 1) m = fmaxf(m, __shfl_xor(m, o, 64));
      const float ex = (lane < deg) ? __expf(ls - m) : 0.f;
      float dsum = ex;
      #pragma unroll
      for (int o = 32; o; o >>= 1) dsum += __shfl_xor(dsum, o, 64);
      if (lane < deg && lane < MAXE) { wvs[t][lane] = v; wws[t][lane] = ex; }
      if (lane == 0) { ms[t] = m; dens[t] = dsum; degs[t] = deg; sts[t] = st; }
    } else {
      float m = -INFINITY;
      for (int j = lane; j < deg; j += 64)
        m = fmaxf(m, leaky(scores[vIdxE[st + j]]));
      #pragma unroll
      for (int o = 32; o; o >>= 1) m = fmaxf(m, __shfl_xor(m, o, 64));
      float dsum = 0.f;
      for (int j = lane; j < deg; j += 64) {
        const int v = vIdxE[st + j];
        const float ex = __expf(leaky(scores[v]) - m);
        dsum += ex;
        if (j < MAXE) { wvs[t][j] = v; wws[t][j] = ex; }
      }
      #pragma unroll
      for (int o = 32; o; o >>= 1) dsum += __shfl_xor(dsum, o, 64);
      if (lane == 0) { ms[t] = m; dens[t] = dsum; degs[t] = deg; sts[t] = st; }
    }
  }
  __syncthreads();

  // phase B: thread handles 2 edges x 4 channels
  const int sub = tid & 31, grp = tid >> 5;
  const int c4 = sub * 4;
  if (sub < 16) {
    const int cs = sub * 4;
    #pragma unroll
    for (int tt = 0; tt < 2; ++tt) {
      const int t = grp*2 + tt;
      const float4 s4 = *(const float4*)&S[(size_t)(e0+t)*STAR_ + cs];
      ushort4 pk; pk.x=f2bf(s4.x); pk.y=f2bf(s4.y); pk.z=f2bf(s4.z); pk.w=f2bf(s4.w);
      *(ushort4*)&msg[t][128 + cs] = pk;
    }
  }
  #pragma unroll
  for (int tt = 0; tt < 2; ++tt) {
    const int t = grp*2 + tt;
    const int deg = degs[t];
    const int dc = deg < MAXE ? deg : MAXE;
    const int dc4 = (dc + 3) & ~3;
    float a0=0.f, a1=0.f, a2=0.f, a3=0.f;
    for (int j = 0; j < dc4; j += 4) {
      #pragma unroll
      for (int ii = 0; ii < 4; ++ii) {
        const int v = wvs[t][j+ii];
        const float wgt = wws[t][j+ii];
        const ushort4 x = *(const ushort4*)&Xfb[(size_t)v*OUTC + c4];
        a0 += wgt * bf2f(x.x); a1 += wgt * bf2f(x.y);
        a2 += wgt * bf2f(x.z); a3 += wgt * bf2f(x.w);
      }
    }
    for (int j = MAXE; j < deg; ++j) {     // statistically never taken
      const int v = vIdxE[sts[t] + j];
      const float wgt = __expf(leaky(scores[v]) - ms[t]);
      const ushort4 x = *(const ushort4*)&Xfb[(size_t)v*OUTC + c4];
      a0 += wgt * bf2f(x.x); a1 += wgt * bf2f(x.y);
      a2 += wgt * bf2f(x.z); a3 += wgt * bf2f(x.w);
    }
    const float invd = deg > 0 ? 1.f/dens[t] : 0.f;
    ushort4 pk;
    pk.x = f2bf(elu1(a0*invd)); pk.y = f2bf(elu1(a1*invd));
    pk.z = f2bf(elu1(a2*invd)); pk.w = f2bf(elu1(a3*invd));
    *(ushort4*)&msg[t][c4] = pk;
  }
  __syncthreads();

  // phase C: Y[16 edges][128] = msg(16x192) @ Wt(192x128) + bt via MFMA
  const int quad = lane >> 4, l16 = lane & 15;
  f32x4_t acc0 = {0,0,0,0}, acc1 = {0,0,0,0};
  const int n0 = w * 32;
  for (int s = 0; s < 6; ++s) {
    const bf16x8_t af = *(const bf16x8_t*)&msg[l16][s*32 + quad*8];
    const bf16x8_t b0 = *(const bf16x8_t*)&WtT[(size_t)(n0 + l16)*192      + s*32 + quad*8];
    const bf16x8_t b1 = *(const bf16x8_t*)&WtT[(size_t)(n0 + 16 + l16)*192 + s*32 + quad*8];
    acc0 = __builtin_amdgcn_mfma_f32_16x16x32_bf16(af, b0, acc0, 0, 0, 0);
    acc1 = __builtin_amdgcn_mfma_f32_16x16x32_bf16(af, b1, acc1, 0, 0, 0);
  }
  const float bt0 = bt[n0 + l16], bt1 = bt[n0 + 16 + l16];
  #pragma unroll
  for (int r = 0; r < 4; ++r) {
    const int m = quad*4 + r;
    Ybf[(size_t)(e0+m)*OUTC + n0 + l16]      = f2bf(acc0[r] + bt0);
    Ybf[(size_t)(e0+m)*OUTC + n0 + 16 + l16] = f2bf(acc1[r] + bt1);
  }
}

// ---- node kernel: scatter-mean(Y[E]) by V, elu, + X_init ----
__global__ __launch_bounds__(128) void k_node(
    const int* __restrict__ cntV, const int* __restrict__ startsV,
    const int* __restrict__ eIdxV,
    const unsigned short* __restrict__ Ybf, float* __restrict__ out) {
  __shared__ int elds[8][MAXN];
  __shared__ int degs[8], sts[8];
  const int tid = threadIdx.x;
  const int lane = tid & 63, w = tid >> 6;
  const int v0 = blockIdx.x * 8;
  #pragma unroll
  for (int p = tid; p < 8*MAXN; p += 128) ((int*)elds)[p] = 0;
  __syncthreads();
  for (int q = 0; q < 4; ++q) {
    const int t = w*4 + q;
    const int v = v0 + t;
    const int deg = cntV[v], st = startsV[v];
    for (int j = lane; j < deg && j < MAXN; j += 64)
      elds[t][j] = eIdxV[st + j];
    if (lane == 0) { degs[t] = deg; sts[t] = st; }
  }
  __syncthreads();
  const int sub = tid & 31, grp = tid >> 5;
  const int c4 = sub * 4;
  #pragma unroll
  for (int tt = 0; tt < 2; ++tt) {
    const int t = grp*2 + tt;
    const int deg = degs[t];
    const int dc = deg < MAXN ? deg : MAXN;
    const int dc4 = (dc + 3) & ~3;
    float a0=0.f, a1=0.f, a2=0.f, a3=0.f;
    for (int j = 0; j < dc4; j += 4) {
      #pragma unroll
      for (int ii = 0; ii < 4; ++ii) {
        const int e = elds[t][j+ii];
        const float pz = (j+ii < dc) ? 1.f : 0.f;
        const ushort4 y = *(const ushort4*)&Ybf[(size_t)e*OUTC + c4];
        a0 += pz * bf2f(y.x); a1 += pz * bf2f(y.y);
        a2 += pz * bf2f(y.z); a3 += pz * bf2f(y.w);
      }
    }
    for (int j = MAXN; j < deg; ++j) {     // statistically never taken
      const int e = eIdxV[sts[t] + j];
      const ushort4 y = *(const ushort4*)&Ybf[(size_t)e*OUTC + c4];
      a0 += bf2f(y.x); a1 += bf2f(y.y); a2 += bf2f(y.z); a3 += bf2f(y.w);
    }
    const float invd = 1.f / fmaxf((float)deg, 1.f);
    float4 o = *(float4*)&out[(size_t)(v0+t)*OUTC + c4];
    o.x = elu1(a0*invd) + o.x;
    o.y = elu1(a1*invd) + o.y;
    o.z = elu1(a2*invd) + o.z;
    o.w = elu1(a3*invd) + o.w;
    *(float4*)&out[(size_t)(v0+t)*OUTC + c4] = o;
  }
}

extern "C" void kernel_launch(void* const* d_in, const int* in_sizes, int n_in,
                              void* d_out, int out_size, void* d_ws, size_t ws_size,
                              hipStream_t stream) {
  const float* X  = (const float*)d_in[0];
  const int*   V  = (const int*)d_in[1];
  const int*   E  = (const int*)d_in[2];
  const float* S  = (const float*)d_in[3];
  const float* Wx = (const float*)d_in[4];
  const float* bx = (const float*)d_in[5];
  const float* Wv = (const float*)d_in[6];
  const float* bv = (const float*)d_in[7];
  const float* av = (const float*)d_in[8];
  const float* Wt = (const float*)d_in[9];
  const float* bt = (const float*)d_in[10];
  float* out = (float*)d_out;

  char* ws = (char*)d_ws;
  size_t off = 0;
  auto alloc = [&](size_t bytes) -> void* {
    off = (off + 255) & ~(size_t)255;
    void* p = ws + off; off += bytes; return p;
  };
  unsigned short* Xfb   = (unsigned short*)alloc((size_t)N_NODES*OUTC*2);
  unsigned short* Ybf   = (unsigned short*)alloc((size_t)N_EDGES*OUTC*2);
  float* scores = (float*)alloc((size_t)N_NODES*4);
  unsigned short* WcatT = (unsigned short*)alloc((size_t)256*128*2);
  unsigned short* WtT   = (unsigned short*)alloc((size_t)128*192*2);
  int* priv = (int*)alloc((size_t)NCOPY*NBUCK*4);   // 9.6 MB privatized counters
  int* cnt  = (int*)alloc((size_t)NBUCK*4);
  int* cntE = cnt;
  int* cntV = cnt + 200000;
  int* startsE = (int*)alloc((size_t)N_EDGES*4);
  int* startsV = (int*)alloc((size_t)N_NODES*4);
  int* vIdxE = (int*)alloc((size_t)NNZ_*4);
  int* eIdxV = (int*)alloc((size_t)NNZ_*4);
  int* partE = (int*)alloc(1024*4);
  int* partV = (int*)alloc(1024*4);

  hipMemsetAsync(priv, 0, (size_t)NCOPY*NBUCK*4, stream);

  k_cvt<<<(256*128 + 128*192 + 255)/256, 256, 0, stream>>>(Wx, Wv, Wt, WcatT, WtT);
  k_gemm1<<<N_NODES/16, 256, 0, stream>>>(X, WcatT, bx, bv, out, Xfb);
  k_scores<<<N_NODES/4, 256, 0, stream>>>(Xfb, av, scores);
  k_hist<<<NNZ_/256, 256, 0, stream>>>(V, E, priv);
  k_total<<<(NBUCK+255)/256, 256, 0, stream>>>(priv, cnt);

  const int nbE = (N_EDGES + 255)/256;   // 782
  const int nbV = (N_NODES + 255)/256;   // 391
  k_scan_block<<<nbE, 256, 0, stream>>>(cntE, startsE, partE, N_EDGES);
  k_scan_partials<<<1, 1024, 0, stream>>>(partE, nbE);
  k_add_off<<<nbE, 256, 0, stream>>>(startsE, partE, N_EDGES);
  k_scan_block<<<nbV, 256, 0, stream>>>(cntV, startsV, partV, N_NODES);
  k_scan_partials<<<1, 1024, 0, stream>>>(partV, nbV);
  k_add_off<<<nbV, 256, 0, stream>>>(startsV, partV, N_NODES);

  k_bases<<<(NBUCK+255)/256, 256, 0, stream>>>(priv, startsE, startsV);
  k_fill<<<NNZ_/256, 256, 0, stream>>>(V, E, priv, vIdxE, eIdxV);
  k_edge<<<N_EDGES/16, 256, 0, stream>>>(cntE, startsE, vIdxE, scores, Xfb, S, WtT, bt, Ybf);
  k_node<<<N_NODES/8, 128, 0, stream>>>(cntV, startsV, eIdxV, Ybf, out);
}

// Round 5
// 524.329 us; speedup vs baseline: 1.6681x; 1.6681x over previous
//
#include <hip/hip_runtime.h>
#include <math.h>

#define N_NODES 100000
#define N_EDGES 200000
#define NNZ_    1600000
#define INC  128
#define OUTC 128
#define STAR_ 64
#define NEG 0.2f
#define MAXE 32     // per-edge cached incidences (deg ~ Poisson(8))
#define MAXN 64     // per-node cached incidences (deg ~ Poisson(16))
#define NBIN_E 391  // ceil(200000/512)
#define NBIN_V 196  // ceil(100000/512)
#define NBIN (NBIN_E + NBIN_V)   // 587
#define CHUNK 4000  // 400 blocks x 4000 = NNZ exactly

typedef __attribute__((ext_vector_type(8))) short bf16x8_t;
typedef __attribute__((ext_vector_type(4))) float f32x4_t;

__device__ __forceinline__ float leaky(float x){ return x > 0.f ? x : NEG*x; }
__device__ __forceinline__ float elu1(float x){ return x > 0.f ? x : __expf(x)-1.f; }
__device__ __forceinline__ unsigned short f2bf(float f){
  unsigned u = __float_as_uint(f);
  unsigned r = u + 0x7FFFu + ((u >> 16) & 1u);
  return (unsigned short)(r >> 16);
}
__device__ __forceinline__ float bf2f(unsigned short h){
  return __uint_as_float(((unsigned)h) << 16);
}

// ---- cvt: WcatT[256][128] = [Wx|Wv]^T bf16 ; WtT[128][192] = Wt^T bf16 ----
__global__ void k_cvt(const float* __restrict__ Wx, const float* __restrict__ Wv,
                      const float* __restrict__ Wt,
                      unsigned short* __restrict__ WcatT, unsigned short* __restrict__ WtT){
  const int i = blockIdx.x*256 + threadIdx.x;
  if (i < 256*128){
    const int n = i >> 7, k = i & 127;
    const float v = (n < 128) ? Wx[k*128 + n] : Wv[k*128 + (n-128)];
    WcatT[n*128 + k] = f2bf(v);
  }
  const int j = i - 256*128;
  if (j >= 0 && j < 128*192){
    const int n = j / 192, k = j - n*192;
    WtT[n*192 + k] = f2bf(Wt[k*128 + n]);
  }
}

// ---- GEMM1 (MFMA): [Xinit|Xfeat] = X @ [Wx|Wv] + [bx|bv]; Xinit fp32 -> d_out, Xfeat bf16 ----
__global__ __launch_bounds__(256) void k_gemm1(const float* __restrict__ X,
    const unsigned short* __restrict__ WcatT,
    const float* __restrict__ bx, const float* __restrict__ bv,
    float* __restrict__ Xinit, unsigned short* __restrict__ Xfb){
  __shared__ unsigned short xb[16][136];
  const int tid = threadIdx.x;
  const int lane = tid & 63, w = tid >> 6;
  const int quad = lane >> 4, l16 = lane & 15;
  const int r0 = blockIdx.x * 16;
  {
    const int r = tid >> 4;
    const int c0 = (tid & 15) * 8;
    const float4 a4 = *(const float4*)&X[(size_t)(r0+r)*INC + c0];
    const float4 b4 = *(const float4*)&X[(size_t)(r0+r)*INC + c0 + 4];
    bf16x8_t pk;
    pk[0]=(short)f2bf(a4.x); pk[1]=(short)f2bf(a4.y); pk[2]=(short)f2bf(a4.z); pk[3]=(short)f2bf(a4.w);
    pk[4]=(short)f2bf(b4.x); pk[5]=(short)f2bf(b4.y); pk[6]=(short)f2bf(b4.z); pk[7]=(short)f2bf(b4.w);
    *(bf16x8_t*)&xb[r][c0] = pk;
  }
  __syncthreads();
  f32x4_t acc[4] = {{0,0,0,0},{0,0,0,0},{0,0,0,0},{0,0,0,0}};
  const int n_base = w*64 + l16;
  for (int s = 0; s < 4; ++s){
    const bf16x8_t af = *(const bf16x8_t*)&xb[l16][s*32 + quad*8];
    #pragma unroll
    for (int nt = 0; nt < 4; ++nt){
      const int n = n_base + nt*16;
      const bf16x8_t bf = *(const bf16x8_t*)&WcatT[(size_t)n*128 + s*32 + quad*8];
      acc[nt] = __builtin_amdgcn_mfma_f32_16x16x32_bf16(af, bf, acc[nt], 0, 0, 0);
    }
  }
  #pragma unroll
  for (int nt = 0; nt < 4; ++nt){
    const int n = n_base + nt*16;
    const float bias = (n < 128) ? bx[n] : bv[n-128];
    #pragma unroll
    for (int r = 0; r < 4; ++r){
      const int m = quad*4 + r;
      const float val = acc[nt][r] + bias;
      if (n < 128) Xinit[(size_t)(r0+m)*OUTC + n] = val;
      else         Xfb[(size_t)(r0+m)*OUTC + (n-128)] = f2bf(val);
    }
  }
}

// ---- scores = Xfeat @ a ----
__global__ __launch_bounds__(256) void k_scores(const unsigned short* __restrict__ Xfb,
    const float* __restrict__ a, float* __restrict__ scores){
  const int lane = threadIdx.x & 63;
  const int w = threadIdx.x >> 6;
  const int r = blockIdx.x * 4 + w;
  const unsigned pair = *(const unsigned*)&Xfb[(size_t)r*OUTC + lane*2];
  float p = bf2f((unsigned short)(pair & 0xffff)) * a[lane*2]
          + bf2f((unsigned short)(pair >> 16))    * a[lane*2+1];
  #pragma unroll
  for (int o = 32; o; o >>= 1) p += __shfl_xor(p, o, 64);
  if (lane == 0) scores[r] = p;
}

// ======== CSR build via two-level binned counting sort ========
// bins: edge bins 0..390 (bucket = e, bin = e>>9), node bins 391..586 (bin = 391 + (v>>9)).
// pair space: E-items occupy [0,NNZ), V-items [NNZ,2*NNZ) (bin bases from one scan).

// exact per-bin totals (block-local LDS hist -> few global atomics)
__global__ __launch_bounds__(256) void k_binhist(const int* __restrict__ V, const int* __restrict__ E,
                                                 int* __restrict__ binCnt){
  __shared__ int h[NBIN];
  for (int p = threadIdx.x; p < NBIN; p += 256) h[p] = 0;
  __syncthreads();
  const int start = blockIdx.x*CHUNK, end = start + CHUNK;
  for (int i = start + threadIdx.x; i < end; i += 256){
    atomicAdd(&h[E[i] >> 9], 1);
    atomicAdd(&h[NBIN_E + (V[i] >> 9)], 1);
  }
  __syncthreads();
  for (int p = threadIdx.x; p < NBIN; p += 256) if (h[p]) atomicAdd(&binCnt[p], h[p]);
}

// exclusive scan over 587 bins; binCur starts at binBase
__global__ __launch_bounds__(1024) void k_binscan(const int* __restrict__ binCnt,
                                                  int* __restrict__ binBase, int* __restrict__ binCur){
  __shared__ int s[1024];
  const int tid = threadIdx.x;
  const int v = (tid < NBIN) ? binCnt[tid] : 0;
  s[tid] = v; __syncthreads();
  for (int o = 1; o < 1024; o <<= 1){
    const int u = (tid >= o) ? s[tid-o] : 0;
    __syncthreads();
    s[tid] += u;
    __syncthreads();
  }
  if (tid < NBIN){ binBase[tid] = s[tid] - v; binCur[tid] = s[tid] - v; }
}

// scatter (key,payload) pairs into bin-contiguous streams
__global__ __launch_bounds__(256) void k_binA(const int* __restrict__ V, const int* __restrict__ E,
                                              int* __restrict__ binCur, int2* __restrict__ pair){
  __shared__ int h[NBIN];
  __shared__ int base[NBIN];
  for (int p = threadIdx.x; p < NBIN; p += 256) h[p] = 0;
  __syncthreads();
  const int start = blockIdx.x*CHUNK, end = start + CHUNK;
  for (int i = start + threadIdx.x; i < end; i += 256){
    atomicAdd(&h[E[i] >> 9], 1);
    atomicAdd(&h[NBIN_E + (V[i] >> 9)], 1);
  }
  __syncthreads();
  for (int p = threadIdx.x; p < NBIN; p += 256)
    base[p] = h[p] ? atomicAdd(&binCur[p], h[p]) : 0;
  __syncthreads();
  for (int p = threadIdx.x; p < NBIN; p += 256) h[p] = 0;   // reuse as local cursor
  __syncthreads();
  for (int i = start + threadIdx.x; i < end; i += 256){
    const int e = E[i], v = V[i];
    const int be = e >> 9, bv = NBIN_E + (v >> 9);
    const int se = base[be] + atomicAdd(&h[be], 1);
    const int sv = base[bv] + atomicAdd(&h[bv], 1);
    pair[se] = make_int2(e, v);
    pair[sv] = make_int2(v, e);
  }
}

// per-bin fine placement; emits cnt/starts as byproducts; writes confined to bin window
__global__ __launch_bounds__(256) void k_binB(const int2* __restrict__ pair,
    const int* __restrict__ binBase, const int* __restrict__ binCnt,
    int* __restrict__ vIdxE, int* __restrict__ eIdxV,
    int* __restrict__ cntE, int* __restrict__ startsE,
    int* __restrict__ cntV, int* __restrict__ startsV){
  __shared__ int h[512], sc0[512], sc1[512];
  const int bin = blockIdx.x;
  const bool isE = bin < NBIN_E;
  const int nb = isE ? bin : bin - NBIN_E;
  const int bucket0 = nb << 9;
  const int nBuckTot = isE ? N_EDGES : N_NODES;
  const int start = binBase[bin];
  const int n = binCnt[bin];
  const int itemBase = isE ? start : start - NNZ_;
  const int tid = threadIdx.x;
  for (int p = tid; p < 512; p += 256) h[p] = 0;
  __syncthreads();
  for (int j = tid; j < n; j += 256) atomicAdd(&h[pair[start + j].x & 511], 1);
  __syncthreads();
  for (int p = tid; p < 512; p += 256) sc0[p] = h[p];
  __syncthreads();
  int* a = sc0; int* b = sc1;
  for (int o = 1; o < 512; o <<= 1){
    for (int p = tid; p < 512; p += 256) b[p] = a[p] + (p >= o ? a[p-o] : 0);
    __syncthreads();
    int* t = a; a = b; b = t;
  }
  // a = inclusive scan; b reused as absolute-slot cursor
  for (int p = tid; p < 512; p += 256){
    const int excl = a[p] - h[p];
    b[p] = itemBase + excl;
    const int bucket = bucket0 + p;
    if (bucket < nBuckTot){
      if (isE){ cntE[bucket] = h[p]; startsE[bucket] = itemBase + excl; }
      else    { cntV[bucket] = h[p]; startsV[bucket] = itemBase + excl; }
    }
  }
  __syncthreads();
  for (int j = tid; j < n; j += 256){
    const int2 kv = pair[start + j];
    const int slot = atomicAdd(&b[kv.x & 511], 1);
    if (isE) vIdxE[slot] = kv.y; else eIdxV[slot] = kv.y;
  }
}

// ---- edge kernel: softmax + v2e aggregate + elu + MFMA [msg,S]@Wt + bt -> Y bf16 ----
__global__ __launch_bounds__(256) void k_edge(
    const int* __restrict__ cntE, const int* __restrict__ startsE,
    const int* __restrict__ vIdxE,
    const float* __restrict__ scores, const unsigned short* __restrict__ Xfb,
    const float* __restrict__ S, const unsigned short* __restrict__ WtT,
    const float* __restrict__ bt, unsigned short* __restrict__ Ybf) {
  __shared__ int   wvs[16][MAXE];
  __shared__ float wws[16][MAXE];
  __shared__ unsigned short msg[16][200];
  __shared__ float ms[16], dens[16];
  __shared__ int   degs[16], sts[16];
  const int tid = threadIdx.x;
  const int lane = tid & 63, w = tid >> 6;
  const int e0 = blockIdx.x * 16;

  for (int p = tid; p < 16*MAXE; p += 256) { ((int*)wvs)[p] = 0; ((float*)wws)[p] = 0.f; }
  __syncthreads();

  for (int q = 0; q < 4; ++q) {
    const int t = w*4 + q;
    const int e = e0 + t;
    const int deg = cntE[e], st = startsE[e];
    if (deg <= 64) {
      int v = 0; float ls = -INFINITY;
      if (lane < deg) { v = vIdxE[st + lane]; ls = leaky(scores[v]); }
      float m = ls;
      #pragma unroll
      for (int o = 32; o; o >>= 1) m = fmaxf(m, __shfl_xor(m, o, 64));
      const float ex = (lane < deg) ? __expf(ls - m) : 0.f;
      float dsum = ex;
      #pragma unroll
      for (int o = 32; o; o >>= 1) dsum += __shfl_xor(dsum, o, 64);
      if (lane < deg && lane < MAXE) { wvs[t][lane] = v; wws[t][lane] = ex; }
      if (lane == 0) { ms[t] = m; dens[t] = dsum; degs[t] = deg; sts[t] = st; }
    } else {
      float m = -INFINITY;
      for (int j = lane; j < deg; j += 64)
        m = fmaxf(m, leaky(scores[vIdxE[st + j]]));
      #pragma unroll
      for (int o = 32; o; o >>= 1) m = fmaxf(m, __shfl_xor(m, o, 64));
      float dsum = 0.f;
      for (int j = lane; j < deg; j += 64) {
        const int v = vIdxE[st + j];
        const float ex = __expf(leaky(scores[v]) - m);
        dsum += ex;
        if (j < MAXE) { wvs[t][j] = v; wws[t][j] = ex; }
      }
      #pragma unroll
      for (int o = 32; o; o >>= 1) dsum += __shfl_xor(dsum, o, 64);
      if (lane == 0) { ms[t] = m; dens[t] = dsum; degs[t] = deg; sts[t] = st; }
    }
  }
  __syncthreads();

  const int sub = tid & 31, grp = tid >> 5;
  const int c4 = sub * 4;
  if (sub < 16) {
    const int cs = sub * 4;
    #pragma unroll
    for (int tt = 0; tt < 2; ++tt) {
      const int t = grp*2 + tt;
      const float4 s4 = *(const float4*)&S[(size_t)(e0+t)*STAR_ + cs];
      ushort4 pk; pk.x=f2bf(s4.x); pk.y=f2bf(s4.y); pk.z=f2bf(s4.z); pk.w=f2bf(s4.w);
      *(ushort4*)&msg[t][128 + cs] = pk;
    }
  }
  #pragma unroll
  for (int tt = 0; tt < 2; ++tt) {
    const int t = grp*2 + tt;
    const int deg = degs[t];
    const int dc = deg < MAXE ? deg : MAXE;
    const int dc4 = (dc + 3) & ~3;
    float a0=0.f, a1=0.f, a2=0.f, a3=0.f;
    for (int j = 0; j < dc4; j += 4) {
      #pragma unroll
      for (int ii = 0; ii < 4; ++ii) {
        const int v = wvs[t][j+ii];
        const float wgt = wws[t][j+ii];
        const ushort4 x = *(const ushort4*)&Xfb[(size_t)v*OUTC + c4];
        a0 += wgt * bf2f(x.x); a1 += wgt * bf2f(x.y);
        a2 += wgt * bf2f(x.z); a3 += wgt * bf2f(x.w);
      }
    }
    for (int j = MAXE; j < deg; ++j) {     // statistically never taken
      const int v = vIdxE[sts[t] + j];
      const float wgt = __expf(leaky(scores[v]) - ms[t]);
      const ushort4 x = *(const ushort4*)&Xfb[(size_t)v*OUTC + c4];
      a0 += wgt * bf2f(x.x); a1 += wgt * bf2f(x.y);
      a2 += wgt * bf2f(x.z); a3 += wgt * bf2f(x.w);
    }
    const float invd = deg > 0 ? 1.f/dens[t] : 0.f;
    ushort4 pk;
    pk.x = f2bf(elu1(a0*invd)); pk.y = f2bf(elu1(a1*invd));
    pk.z = f2bf(elu1(a2*invd)); pk.w = f2bf(elu1(a3*invd));
    *(ushort4*)&msg[t][c4] = pk;
  }
  __syncthreads();

  const int quad = lane >> 4, l16 = lane & 15;
  f32x4_t acc0 = {0,0,0,0}, acc1 = {0,0,0,0};
  const int n0 = w * 32;
  for (int s = 0; s < 6; ++s) {
    const bf16x8_t af = *(const bf16x8_t*)&msg[l16][s*32 + quad*8];
    const bf16x8_t b0 = *(const bf16x8_t*)&WtT[(size_t)(n0 + l16)*192      + s*32 + quad*8];
    const bf16x8_t b1 = *(const bf16x8_t*)&WtT[(size_t)(n0 + 16 + l16)*192 + s*32 + quad*8];
    acc0 = __builtin_amdgcn_mfma_f32_16x16x32_bf16(af, b0, acc0, 0, 0, 0);
    acc1 = __builtin_amdgcn_mfma_f32_16x16x32_bf16(af, b1, acc1, 0, 0, 0);
  }
  const float bt0 = bt[n0 + l16], bt1 = bt[n0 + 16 + l16];
  #pragma unroll
  for (int r = 0; r < 4; ++r) {
    const int m = quad*4 + r;
    Ybf[(size_t)(e0+m)*OUTC + n0 + l16]      = f2bf(acc0[r] + bt0);
    Ybf[(size_t)(e0+m)*OUTC + n0 + 16 + l16] = f2bf(acc1[r] + bt1);
  }
}

// ---- node kernel: scatter-mean(Y[E]) by V, elu, + X_init ----
__global__ __launch_bounds__(128) void k_node(
    const int* __restrict__ cntV, const int* __restrict__ startsV,
    const int* __restrict__ eIdxV,
    const unsigned short* __restrict__ Ybf, float* __restrict__ out) {
  __shared__ int elds[8][MAXN];
  __shared__ int degs[8], sts[8];
  const int tid = threadIdx.x;
  const int lane = tid & 63, w = tid >> 6;
  const int v0 = blockIdx.x * 8;
  #pragma unroll
  for (int p = tid; p < 8*MAXN; p += 128) ((int*)elds)[p] = 0;
  __syncthreads();
  for (int q = 0; q < 4; ++q) {
    const int t = w*4 + q;
    const int v = v0 + t;
    const int deg = cntV[v], st = startsV[v];
    for (int j = lane; j < deg && j < MAXN; j += 64)
      elds[t][j] = eIdxV[st + j];
    if (lane == 0) { degs[t] = deg; sts[t] = st; }
  }
  __syncthreads();
  const int sub = tid & 31, grp = tid >> 5;
  const int c4 = sub * 4;
  #pragma unroll
  for (int tt = 0; tt < 2; ++tt) {
    const int t = grp*2 + tt;
    const int deg = degs[t];
    const int dc = deg < MAXN ? deg : MAXN;
    const int dc4 = (dc + 3) & ~3;
    float a0=0.f, a1=0.f, a2=0.f, a3=0.f;
    for (int j = 0; j < dc4; j += 4) {
      #pragma unroll
      for (int ii = 0; ii < 4; ++ii) {
        const int e = elds[t][j+ii];
        const float pz = (j+ii < dc) ? 1.f : 0.f;
        const ushort4 y = *(const ushort4*)&Ybf[(size_t)e*OUTC + c4];
        a0 += pz * bf2f(y.x); a1 += pz * bf2f(y.y);
        a2 += pz * bf2f(y.z); a3 += pz * bf2f(y.w);
      }
    }
    for (int j = MAXN; j < deg; ++j) {     // statistically never taken
      const int e = eIdxV[sts[t] + j];
      const ushort4 y = *(const ushort4*)&Ybf[(size_t)e*OUTC + c4];
      a0 += bf2f(y.x); a1 += bf2f(y.y); a2 += bf2f(y.z); a3 += bf2f(y.w);
    }
    const float invd = 1.f / fmaxf((float)deg, 1.f);
    float4 o = *(float4*)&out[(size_t)(v0+t)*OUTC + c4];
    o.x = elu1(a0*invd) + o.x;
    o.y = elu1(a1*invd) + o.y;
    o.z = elu1(a2*invd) + o.z;
    o.w = elu1(a3*invd) + o.w;
    *(float4*)&out[(size_t)(v0+t)*OUTC + c4] = o;
  }
}

extern "C" void kernel_launch(void* const* d_in, const int* in_sizes, int n_in,
                              void* d_out, int out_size, void* d_ws, size_t ws_size,
                              hipStream_t stream) {
  const float* X  = (const float*)d_in[0];
  const int*   V  = (const int*)d_in[1];
  const int*   E  = (const int*)d_in[2];
  const float* S  = (const float*)d_in[3];
  const float* Wx = (const float*)d_in[4];
  const float* bx = (const float*)d_in[5];
  const float* Wv = (const float*)d_in[6];
  const float* bv = (const float*)d_in[7];
  const float* av = (const float*)d_in[8];
  const float* Wt = (const float*)d_in[9];
  const float* bt = (const float*)d_in[10];
  float* out = (float*)d_out;

  char* ws = (char*)d_ws;
  size_t off = 0;
  auto alloc = [&](size_t bytes) -> void* {
    off = (off + 255) & ~(size_t)255;
    void* p = ws + off; off += bytes; return p;
  };
  unsigned short* Xfb   = (unsigned short*)alloc((size_t)N_NODES*OUTC*2);
  unsigned short* Ybf   = (unsigned short*)alloc((size_t)N_EDGES*OUTC*2);
  float* scores = (float*)alloc((size_t)N_NODES*4);
  unsigned short* WcatT = (unsigned short*)alloc((size_t)256*128*2);
  unsigned short* WtT   = (unsigned short*)alloc((size_t)128*192*2);
  int2* pair   = (int2*)alloc((size_t)2*NNZ_*8);       // 25.6 MB
  int* binCnt  = (int*)alloc((size_t)NBIN*4);
  int* binBase = (int*)alloc((size_t)NBIN*4);
  int* binCur  = (int*)alloc((size_t)NBIN*4);
  int* cntE    = (int*)alloc((size_t)N_EDGES*4);
  int* cntV    = (int*)alloc((size_t)N_NODES*4);
  int* startsE = (int*)alloc((size_t)N_EDGES*4);
  int* startsV = (int*)alloc((size_t)N_NODES*4);
  int* vIdxE   = (int*)alloc((size_t)NNZ_*4);
  int* eIdxV   = (int*)alloc((size_t)NNZ_*4);

  hipMemsetAsync(binCnt, 0, (size_t)NBIN*4, stream);

  k_cvt<<<(256*128 + 128*192 + 255)/256, 256, 0, stream>>>(Wx, Wv, Wt, WcatT, WtT);
  k_gemm1<<<N_NODES/16, 256, 0, stream>>>(X, WcatT, bx, bv, out, Xfb);
  k_scores<<<N_NODES/4, 256, 0, stream>>>(Xfb, av, scores);

  k_binhist<<<NNZ_/CHUNK, 256, 0, stream>>>(V, E, binCnt);
  k_binscan<<<1, 1024, 0, stream>>>(binCnt, binBase, binCur);
  k_binA<<<NNZ_/CHUNK, 256, 0, stream>>>(V, E, binCur, pair);
  k_binB<<<NBIN, 256, 0, stream>>>(pair, binBase, binCnt, vIdxE, eIdxV,
                                   cntE, startsE, cntV, startsV);

  k_edge<<<N_EDGES/16, 256, 0, stream>>>(cntE, startsE, vIdxE, scores, Xfb, S, WtT, bt, Ybf);
  k_node<<<N_NODES/8, 128, 0, stream>>>(cntV, startsV, eIdxV, Ybf, out);
}